// Round 4
// baseline (1977.776 us; speedup 1.0000x reference)
//
#include <hip/hip_runtime.h>
#include <cstdint>
#include <cstddef>

// Problem constants (Swin window attention)
#define B_WIN   2048
#define N_TOK   64
#define C_DIM   512
#define H_HEADS 16
#define D_HEAD  32
#define K_DIM   512
#define M_ROWS  (B_WIN * N_TOK)   // 131072

typedef __bf16 bf16x8 __attribute__((ext_vector_type(8)));
typedef float  f32x4  __attribute__((ext_vector_type(4)));
typedef unsigned short u16x8 __attribute__((ext_vector_type(8)));

__device__ __forceinline__ unsigned short f2bf_rn(float f) {
    unsigned u = __float_as_uint(f);
    u += 0x7fffu + ((u >> 16) & 1u);
    return (unsigned short)(u >> 16);
}
__device__ __forceinline__ float bf2f(unsigned short h) {
    return __uint_as_float(((unsigned)h) << 16);
}
__device__ __forceinline__ void gload16(const void* g, void* l) {
    __builtin_amdgcn_global_load_lds(
        (const __attribute__((address_space(1))) void*)g,
        (__attribute__((address_space(3))) void*)l,
        16, 0, 0);
}

// ---------------------------------------------------------------------------
// xsplit: A [M][512] fp32 -> Ah/Al [M][512] bf16 (hi/lo residual split)
// ---------------------------------------------------------------------------
__global__ __launch_bounds__(256) void xsplit_kernel(
    const float* __restrict__ x,
    unsigned short* __restrict__ Xh,
    unsigned short* __restrict__ Xl)
{
    size_t i = ((size_t)blockIdx.x * 256 + threadIdx.x) * 8;
    float4 f0 = *reinterpret_cast<const float4*>(&x[i]);
    float4 f1 = *reinterpret_cast<const float4*>(&x[i + 4]);
    float fv[8] = {f0.x, f0.y, f0.z, f0.w, f1.x, f1.y, f1.z, f1.w};
    u16x8 hi, lo;
#pragma unroll
    for (int j = 0; j < 8; ++j) {
        unsigned short h = f2bf_rn(fv[j]);
        hi[j] = h;
        lo[j] = f2bf_rn(fv[j] - bf2f(h));
    }
    *reinterpret_cast<u16x8*>(&Xh[i]) = hi;
    *reinterpret_cast<u16x8*>(&Xl[i]) = lo;
}

// ---------------------------------------------------------------------------
// Weight transpose + bf16 hi/lo split: w[K=512][N] -> wTh/wTl[N][512]
// ---------------------------------------------------------------------------
__global__ __launch_bounds__(256) void wsplit_kernel(
    const float* __restrict__ w,
    unsigned short* __restrict__ wTh,
    unsigned short* __restrict__ wTl,
    int Ncols)
{
    int idx = blockIdx.x * 256 + threadIdx.x;   // idx = n*512 + k
    int n = idx >> 9;
    int k = idx & 511;
    float v = w[(size_t)k * Ncols + n];
    unsigned short hi = f2bf_rn(v);
    wTh[idx] = hi;
    wTl[idx] = f2bf_rn(v - bf2f(hi));
}

// ---------------------------------------------------------------------------
// bf16x3-split MFMA GEMM via virtual K = 1536:
//   pass 0: Ah*Bh   pass 1: Ah*Bl   pass 2: Al*Bh   (Al*Bl ~ 2^-32, dropped)
// 128x128 tile, 4 waves, BK=32 per step, 48 steps. 3-buffer LDS (48 KiB),
// 2-deep prefetch, ONE raw s_barrier per step, counted vmcnt(4) (never 0
// in-loop), setprio around MFMA, bijective XCD-swizzled block mapping.
//   mode 0: scatter into qkv[3][B][H][N][D]
//   mode 1: add bias, store row-major [M][Ncols_out]
// ---------------------------------------------------------------------------
__global__ __launch_bounds__(256) void gemm_mfma_kernel(
    const unsigned short* __restrict__ ATh,  // [M][512]
    const unsigned short* __restrict__ ATl,
    const unsigned short* __restrict__ BTh,  // [N][512]
    const unsigned short* __restrict__ BTl,
    int mode,
    float* __restrict__ qkv_out,
    const float* __restrict__ bias,
    float* __restrict__ out,
    int Ncols_out,
    int nb_grid)                             // blocks along n (Ncols/128)
{
    __shared__ __align__(16) unsigned short Abuf[3][4096];  // [128 m][32 k] each
    __shared__ __align__(16) unsigned short Bbuf[3][4096];  // [128 n][32 k] each

    const int t    = threadIdx.x;
    const int lane = t & 63;
    const int wave = t >> 6;
    const int lg   = lane >> 4;      // 0..3  (k-group)
    const int lr   = lane & 15;      // 0..15 (m / n within fragment)
    const int wrow = (wave >> 1) * 64;
    const int wcol = (wave & 1) * 64;

    // T1: bijective XCD swizzle (nwg % 8 == 0 for both launch shapes)
    const int lin = blockIdx.x + gridDim.x * blockIdx.y;
    const int nwg = gridDim.x * gridDim.y;
    const int cpx = nwg >> 3;
    const int swz = (lin & 7) * cpx + (lin >> 3);
    const int m0  = (swz / nb_grid) * 128;
    const int n0  = (swz % nb_grid) * 128;

    f32x4 acc[4][4];
#pragma unroll
    for (int i = 0; i < 4; ++i)
#pragma unroll
        for (int j = 0; j < 4; ++j) acc[i][j] = (f32x4){0.f, 0.f, 0.f, 0.f};

    // stage one 16KB step (A-tile + B-tile) into buffer bi: 4 gloads/thread
    auto stage = [&](int ks, int bi) {
        const int pass = ks >> 4;                 // 0..2
        const int kk   = (ks & 15) << 5;          // real-k offset
        const unsigned short* As = (pass < 2)  ? ATh : ATl;
        const unsigned short* Bs = (pass == 1) ? BTl : BTh;
#pragma unroll
        for (int i = 0; i < 2; ++i) {
            const int c    = i * 256 + t;         // 16B chunk id, wave-contig
            const int row  = c >> 2;              // 0..127
            const int slot = (c & 3) * 8;         // bf16 elems within row
            gload16(&As[(size_t)(m0 + row) * 512 + kk + slot], &Abuf[bi][c * 8]);
            gload16(&Bs[(size_t)(n0 + row) * 512 + kk + slot], &Bbuf[bi][c * 8]);
        }
    };

    // prologue: 2-deep prefetch
    stage(0, 0);
    stage(1, 1);
    asm volatile("s_waitcnt vmcnt(4)" ::: "memory");   // tile 0 landed
    __builtin_amdgcn_sched_barrier(0);
    __builtin_amdgcn_s_barrier();
    __builtin_amdgcn_sched_barrier(0);

#pragma unroll 3
    for (int ks = 0; ks < 48; ++ks) {
        const int rb = ks % 3;                    // read buffer
        stage((ks + 2) % 48, (ks + 2) % 3);       // wrapped tail: dead buffers

        const unsigned short* Ab = Abuf[rb];
        const unsigned short* Bb = Bbuf[rb];
        bf16x8 af[4], bf[4];
#pragma unroll
        for (int mi = 0; mi < 4; ++mi)
            af[mi] = *reinterpret_cast<const bf16x8*>(&Ab[(wrow + mi * 16 + lr) * 32 + lg * 8]);
#pragma unroll
        for (int ni = 0; ni < 4; ++ni)
            bf[ni] = *reinterpret_cast<const bf16x8*>(&Bb[(wcol + ni * 16 + lr) * 32 + lg * 8]);

        __builtin_amdgcn_s_setprio(1);
#pragma unroll
        for (int ni = 0; ni < 4; ++ni)
#pragma unroll
            for (int mi = 0; mi < 4; ++mi)
                acc[mi][ni] = __builtin_amdgcn_mfma_f32_16x16x32_bf16(af[mi], bf[ni], acc[mi][ni], 0, 0, 0);
        __builtin_amdgcn_s_setprio(0);

        asm volatile("s_waitcnt vmcnt(4)" ::: "memory");  // next tile landed
        __builtin_amdgcn_sched_barrier(0);
        __builtin_amdgcn_s_barrier();
        __builtin_amdgcn_sched_barrier(0);
    }
    asm volatile("s_waitcnt vmcnt(0)" ::: "memory");      // drain before teardown

    // C/D layout: col = lane&15, row = (lane>>4)*4 + reg   [m89-verified]
    if (mode == 0) {
#pragma unroll
        for (int mi = 0; mi < 4; ++mi)
#pragma unroll
            for (int ni = 0; ni < 4; ++ni) {
                const int col  = n0 + wcol + ni * 16 + lr;
                const int tsel = col >> 9;
                const int h    = (col >> 5) & 15;
                const int dd   = col & 31;
#pragma unroll
                for (int reg = 0; reg < 4; ++reg) {
                    const int row = m0 + wrow + mi * 16 + lg * 4 + reg;
                    const int b = row >> 6, n = row & 63;
                    qkv_out[((((size_t)tsel * B_WIN + b) * H_HEADS + h) * N_TOK + n) * D_HEAD + dd]
                        = acc[mi][ni][reg];
                }
            }
    } else {
#pragma unroll
        for (int mi = 0; mi < 4; ++mi)
#pragma unroll
            for (int ni = 0; ni < 4; ++ni) {
                const int col = n0 + wcol + ni * 16 + lr;
                const float pb = bias[col];
#pragma unroll
                for (int reg = 0; reg < 4; ++reg) {
                    const int row = m0 + wrow + mi * 16 + lg * 4 + reg;
                    out[(size_t)row * Ncols_out + col] = acc[mi][ni][reg] + pb;
                }
            }
    }
}

// ---------------------------------------------------------------------------
// Kernel 2: per-(b,h) window attention; emits av pre-split as avh/avl bf16
// ---------------------------------------------------------------------------
__global__ __launch_bounds__(256) void attn_kernel(
    const float* __restrict__ qkv,        // [3][B][H][N][D]
    const float* __restrict__ bias_table, // [(2ws-1)^2][H]
    const int*   __restrict__ rel_index,  // [64][64]
    float* __restrict__ attn_map,         // [B][H][64][64]
    unsigned short* __restrict__ avh,     // [B][N][H][D] = [M][512] bf16 hi
    unsigned short* __restrict__ avl)     // lo
{
    __shared__ float qs[64][36];
    __shared__ float ks[64][36];
    __shared__ float vs[64][36];
    __shared__ float ps[64][65];

    const int bh = blockIdx.x;
    const int b  = bh >> 4;
    const int h  = bh & 15;
    const int t  = threadIdx.x;

    const size_t plane = (size_t)B_WIN * H_HEADS * N_TOK * D_HEAD;
    const size_t base  = (size_t)bh * (N_TOK * D_HEAD);
    const float* qg = qkv + base;
    const float* kg = qkv + plane + base;
    const float* vg = qkv + 2 * plane + base;

    const int lr = t >> 2;
    const int lc = (t & 3) * 8;
    {
        float4 x0 = *reinterpret_cast<const float4*>(&qg[lr * 32 + lc]);
        float4 x1 = *reinterpret_cast<const float4*>(&qg[lr * 32 + lc + 4]);
        *reinterpret_cast<float4*>(&qs[lr][lc])     = x0;
        *reinterpret_cast<float4*>(&qs[lr][lc + 4]) = x1;
        float4 y0 = *reinterpret_cast<const float4*>(&kg[lr * 32 + lc]);
        float4 y1 = *reinterpret_cast<const float4*>(&kg[lr * 32 + lc + 4]);
        *reinterpret_cast<float4*>(&ks[lr][lc])     = y0;
        *reinterpret_cast<float4*>(&ks[lr][lc + 4]) = y1;
        float4 z0 = *reinterpret_cast<const float4*>(&vg[lr * 32 + lc]);
        float4 z1 = *reinterpret_cast<const float4*>(&vg[lr * 32 + lc + 4]);
        *reinterpret_cast<float4*>(&vs[lr][lc])     = z0;
        *reinterpret_cast<float4*>(&vs[lr][lc + 4]) = z1;
    }
    __syncthreads();

    const int r  = t >> 2;
    const int c0 = (t & 3) * 16;

    float qr[32];
#pragma unroll
    for (int u = 0; u < 8; ++u) {
        float4 qf = *reinterpret_cast<const float4*>(&qs[r][u * 4]);
        qr[u * 4 + 0] = qf.x; qr[u * 4 + 1] = qf.y;
        qr[u * 4 + 2] = qf.z; qr[u * 4 + 3] = qf.w;
    }

    const float scale = 0.1767766952966369f;  // 32^-0.5
    float p[16];
#pragma unroll
    for (int j = 0; j < 16; ++j) {
        const int c = c0 + j;
        float s = 0.f;
#pragma unroll
        for (int kk = 0; kk < 32; kk += 4) {
            float4 kf = *reinterpret_cast<const float4*>(&ks[c][kk]);
            s = fmaf(qr[kk + 0], kf.x, s);
            s = fmaf(qr[kk + 1], kf.y, s);
            s = fmaf(qr[kk + 2], kf.z, s);
            s = fmaf(qr[kk + 3], kf.w, s);
        }
        p[j] = fmaf(s, scale, bias_table[rel_index[(r << 6) + c] * H_HEADS + h]);
    }

    float mx = p[0];
#pragma unroll
    for (int j = 1; j < 16; ++j) mx = fmaxf(mx, p[j]);
    mx = fmaxf(mx, __shfl_xor(mx, 1));
    mx = fmaxf(mx, __shfl_xor(mx, 2));
    float sum = 0.f;
#pragma unroll
    for (int j = 0; j < 16; ++j) { p[j] = __expf(p[j] - mx); sum += p[j]; }
    sum += __shfl_xor(sum, 1);
    sum += __shfl_xor(sum, 2);
    const float inv = 1.0f / sum;
#pragma unroll
    for (int j = 0; j < 16; ++j) p[j] *= inv;

#pragma unroll
    for (int j = 0; j < 16; ++j) ps[r][c0 + j] = p[j];

    {
        size_t ab = ((size_t)bh * 64 + r) * 64 + c0;
        *reinterpret_cast<float4*>(&attn_map[ab + 0])  = make_float4(p[0],  p[1],  p[2],  p[3]);
        *reinterpret_cast<float4*>(&attn_map[ab + 4])  = make_float4(p[4],  p[5],  p[6],  p[7]);
        *reinterpret_cast<float4*>(&attn_map[ab + 8])  = make_float4(p[8],  p[9],  p[10], p[11]);
        *reinterpret_cast<float4*>(&attn_map[ab + 12]) = make_float4(p[12], p[13], p[14], p[15]);
    }
    __syncthreads();

    const int dd0 = (t & 3) * 8;
    float acc[8];
#pragma unroll
    for (int u = 0; u < 8; ++u) acc[u] = 0.f;
#pragma unroll 8
    for (int j = 0; j < 64; ++j) {
        const float pv = ps[r][j];
        float4 v0 = *reinterpret_cast<const float4*>(&vs[j][dd0]);
        float4 v1 = *reinterpret_cast<const float4*>(&vs[j][dd0 + 4]);
        acc[0] = fmaf(pv, v0.x, acc[0]);
        acc[1] = fmaf(pv, v0.y, acc[1]);
        acc[2] = fmaf(pv, v0.z, acc[2]);
        acc[3] = fmaf(pv, v0.w, acc[3]);
        acc[4] = fmaf(pv, v1.x, acc[4]);
        acc[5] = fmaf(pv, v1.y, acc[5]);
        acc[6] = fmaf(pv, v1.z, acc[6]);
        acc[7] = fmaf(pv, v1.w, acc[7]);
    }
    // emit pre-split hi/lo bf16 (feeds proj GEMM's MFMA path directly)
    u16x8 hv, lv;
#pragma unroll
    for (int u = 0; u < 8; ++u) {
        unsigned short hh = f2bf_rn(acc[u]);
        hv[u] = hh;
        lv[u] = f2bf_rn(acc[u] - bf2f(hh));
    }
    size_t o = (((size_t)b * 64 + r) * 16 + h) * 32 + dd0;
    *reinterpret_cast<u16x8*>(&avh[o]) = hv;
    *reinterpret_cast<u16x8*>(&avl[o]) = lv;
}

// ---------------------------------------------------------------------------
extern "C" void kernel_launch(void* const* d_in, const int* in_sizes, int n_in,
                              void* d_out, int out_size, void* d_ws, size_t ws_size,
                              hipStream_t stream) {
    const float* x          = (const float*)d_in[0];
    const float* qkv_w      = (const float*)d_in[1];
    const float* proj_w     = (const float*)d_in[2];
    const float* proj_b     = (const float*)d_in[3];
    const float* bias_table = (const float*)d_in[4];
    const int*   rel_index  = (const int*)d_in[5];

    float* out      = (float*)d_out;                           // [131072][512]
    float* attn_map = (float*)d_out + (size_t)M_ROWS * C_DIM;  // [B][H][64][64]

    // d_ws layout (exactly 1 GiB):
    //   Xh [M][512] bf16 | Xl [M][512] bf16 | qkv [3][B][H][N][D] fp32
    // avh/avl alias Xh/Xl (dead after QKV GEMM; attn writes them after).
    unsigned short* Xh  = (unsigned short*)d_ws;
    unsigned short* Xl  = Xh + (size_t)M_ROWS * 512;
    float*          qkv = (float*)(Xl + (size_t)M_ROWS * 512);
    unsigned short* avh = Xh;
    unsigned short* avl = Xl;

    // qkv_w split parks in the attn_map region of d_out (dead until attn,
    // which fully overwrites it). proj_w split parks at qkv head (dead after
    // attn reads qkv; wsplit launches after attn in stream order).
    unsigned short* qwTh = (unsigned short*)attn_map;
    unsigned short* qwTl = qwTh + (size_t)1536 * 512;
    unsigned short* pwTh = (unsigned short*)qkv;
    unsigned short* pwTl = pwTh + (size_t)512 * 512;

    xsplit_kernel<<<M_ROWS * 512 / 2048, 256, 0, stream>>>(x, Xh, Xl);
    wsplit_kernel<<<3072, 256, 0, stream>>>(qkv_w, qwTh, qwTl, 1536);
    gemm_mfma_kernel<<<dim3(12, 1024), 256, 0, stream>>>(
        Xh, Xl, qwTh, qwTl, 0, qkv, nullptr, nullptr, 1536, 12);
    attn_kernel<<<B_WIN * H_HEADS, 256, 0, stream>>>(
        qkv, bias_table, rel_index, attn_map, avh, avl);
    wsplit_kernel<<<1024, 256, 0, stream>>>(proj_w, pwTh, pwTl, 512);
    gemm_mfma_kernel<<<dim3(4, 1024), 256, 0, stream>>>(
        avh, avl, pwTh, pwTl, 1, nullptr, proj_b, out, 512, 4);
}

// Round 5
// 1540.082 us; speedup vs baseline: 1.2842x; 1.2842x over previous
//
#include <hip/hip_runtime.h>
#include <cstdint>
#include <cstddef>

// Problem constants (Swin window attention)
#define B_WIN   2048
#define N_TOK   64
#define C_DIM   512
#define H_HEADS 16
#define D_HEAD  32
#define K_DIM   512
#define M_ROWS  (B_WIN * 64)   // 131072

// Tiled operand layout for GEMM staging (bf16):
//   T[mb][kt][s][r][e]  mb=row>>7, kt=k>>5, s=(k>>3)&3, r=row&127, e=k&7
//   flat elem = mb*65536 + kt*4096 + s*1024 + r*8 + e
// -> stage of one 128x32 tile = 8KB contiguous; frag ds_read conflict-free.

typedef __bf16 bf16x8 __attribute__((ext_vector_type(8)));
typedef float  f32x4  __attribute__((ext_vector_type(4)));
typedef unsigned short u16x8 __attribute__((ext_vector_type(8)));

__device__ __forceinline__ unsigned short f2bf_rn(float f) {
    unsigned u = __float_as_uint(f);
    u += 0x7fffu + ((u >> 16) & 1u);
    return (unsigned short)(u >> 16);
}
__device__ __forceinline__ float bf2f(unsigned short h) {
    return __uint_as_float(((unsigned)h) << 16);
}
__device__ __forceinline__ void gload16(const void* g, void* l) {
    __builtin_amdgcn_global_load_lds(
        (const __attribute__((address_space(1))) void*)g,
        (__attribute__((address_space(3))) void*)l,
        16, 0, 0);
}

// ---------------------------------------------------------------------------
// xsplit: x [M][512] fp32 -> Xh/Xl bf16 hi/lo in TILED layout.
// Thread i writes output chunk i (coalesced); reads 32B strided (stride 2KB).
// ---------------------------------------------------------------------------
__global__ __launch_bounds__(256) void xsplit_kernel(
    const float* __restrict__ x,
    unsigned short* __restrict__ Xh,
    unsigned short* __restrict__ Xl)
{
    size_t e8 = ((size_t)blockIdx.x * 256 + threadIdx.x) * 8;
    const int mb = (int)(e8 >> 16);
    const int w  = (int)(e8 & 65535);
    const int kt = w >> 12;
    const int s  = (w >> 10) & 3;
    const int r  = (w >> 3) & 127;
    const int m  = mb * 128 + r;
    const int k  = kt * 32 + s * 8;
    const float* src = &x[(size_t)m * 512 + k];
    float4 f0 = *reinterpret_cast<const float4*>(src);
    float4 f1 = *reinterpret_cast<const float4*>(src + 4);
    float fv[8] = {f0.x, f0.y, f0.z, f0.w, f1.x, f1.y, f1.z, f1.w};
    u16x8 hi, lo;
#pragma unroll
    for (int j = 0; j < 8; ++j) {
        unsigned short h = f2bf_rn(fv[j]);
        hi[j] = h;
        lo[j] = f2bf_rn(fv[j] - bf2f(h));
    }
    *reinterpret_cast<u16x8*>(&Xh[e8]) = hi;
    *reinterpret_cast<u16x8*>(&Xl[e8]) = lo;
}

// ---------------------------------------------------------------------------
// wsplit: w[512 k][Ncols n] -> wTh/wTl (rows=n, 512 k) in TILED layout
// ---------------------------------------------------------------------------
__global__ __launch_bounds__(256) void wsplit_kernel(
    const float* __restrict__ w,
    unsigned short* __restrict__ wTh,
    unsigned short* __restrict__ wTl,
    int Ncols)
{
    size_t e8 = ((size_t)blockIdx.x * 256 + threadIdx.x) * 8;
    const int mb = (int)(e8 >> 16);
    const int ww = (int)(e8 & 65535);
    const int kt = ww >> 12;
    const int s  = (ww >> 10) & 3;
    const int r  = (ww >> 3) & 127;
    const int n  = mb * 128 + r;
    const int k  = kt * 32 + s * 8;
    u16x8 hi, lo;
#pragma unroll
    for (int j = 0; j < 8; ++j) {
        float v = w[(size_t)(k + j) * Ncols + n];
        unsigned short h = f2bf_rn(v);
        hi[j] = h;
        lo[j] = f2bf_rn(v - bf2f(h));
    }
    *reinterpret_cast<u16x8*>(&wTh[e8]) = hi;
    *reinterpret_cast<u16x8*>(&wTl[e8]) = lo;
}

// ---------------------------------------------------------------------------
// bf16x3-split MFMA GEMM, 128x128 tile, BK=32, 16 steps, 48 MFMA/step.
// Double-buffered (2x32KB), 1-deep prefetch, single barrier + vmcnt(0) AFTER
// the MFMA cluster (loads drain under compute), setprio, XCD swizzle.
// Operands in tiled layout -> contiguous staging, conflict-free ds_read.
// ---------------------------------------------------------------------------
__global__ __launch_bounds__(256) void gemm_mfma_kernel(
    const unsigned short* __restrict__ ATh,
    const unsigned short* __restrict__ ATl,
    const unsigned short* __restrict__ BTh,
    const unsigned short* __restrict__ BTl,
    int mode,
    float* __restrict__ qkv_out,
    const float* __restrict__ bias,
    float* __restrict__ out,
    int Ncols_out,
    int nb_grid)
{
    // [buf][op][4096 elems]; op: 0=Ah 1=Al 2=Bh 3=Bl   (64 KiB total)
    __shared__ __align__(16) unsigned short L[2][4][4096];

    const int t    = threadIdx.x;
    const int lane = t & 63;
    const int wave = t >> 6;
    const int lg   = lane >> 4;      // k-octet 0..3
    const int lr   = lane & 15;      // row within fragment
    const int wrow = (wave >> 1) * 64;
    const int wcol = (wave & 1) * 64;

    // bijective XCD swizzle (nwg % 8 == 0 for both launch shapes)
    const int lin = blockIdx.x + gridDim.x * blockIdx.y;
    const int nwg = gridDim.x * gridDim.y;
    const int cpx = nwg >> 3;
    const int swz = (lin & 7) * cpx + (lin >> 3);
    const int m0  = (swz / nb_grid) * 128;
    const int n0  = (swz % nb_grid) * 128;
    const size_t tbA = (size_t)(m0 >> 7) * 16 * 4096;  // tile base (elems)
    const size_t tbB = (size_t)(n0 >> 7) * 16 * 4096;

    f32x4 acc[4][4];
#pragma unroll
    for (int i = 0; i < 4; ++i)
#pragma unroll
        for (int j = 0; j < 4; ++j) acc[i][j] = (f32x4){0.f, 0.f, 0.f, 0.f};

    // stage all 4 operand tiles for K-step kt into buffer bi (8 gloads)
    auto stage = [&](int kt, int bi) {
        const size_t bA = tbA + (size_t)kt * 4096;
        const size_t bB = tbB + (size_t)kt * 4096;
#pragma unroll
        for (int i = 0; i < 2; ++i) {
            const int c = i * 256 + t;   // chunk 0..511, wave-contiguous
            gload16(&ATh[bA + c * 8], &L[bi][0][c * 8]);
            gload16(&ATl[bA + c * 8], &L[bi][1][c * 8]);
            gload16(&BTh[bB + c * 8], &L[bi][2][c * 8]);
            gload16(&BTl[bB + c * 8], &L[bi][3][c * 8]);
        }
    };

    stage(0, 0);
    asm volatile("s_waitcnt vmcnt(0)" ::: "memory");
    __builtin_amdgcn_sched_barrier(0);
    __builtin_amdgcn_s_barrier();
    __builtin_amdgcn_sched_barrier(0);

#pragma unroll 2
    for (int ks = 0; ks < 16; ++ks) {
        const int cur = ks & 1;
        if (ks + 1 < 16) stage(ks + 1, cur ^ 1);

        // fragment reads: lg-major tile layout -> 16-lane groups read 256B
        // contiguous spans (bank-conflict-free)
        bf16x8 ah[4], al[4];
#pragma unroll
        for (int mi = 0; mi < 4; ++mi) {
            const int off = lg * 1024 + (wrow + mi * 16 + lr) * 8;
            ah[mi] = *reinterpret_cast<const bf16x8*>(&L[cur][0][off]);
            al[mi] = *reinterpret_cast<const bf16x8*>(&L[cur][1][off]);
        }
        __builtin_amdgcn_s_setprio(1);
#pragma unroll
        for (int ni = 0; ni < 4; ++ni) {
            const int off = lg * 1024 + (wcol + ni * 16 + lr) * 8;
            bf16x8 bh = *reinterpret_cast<const bf16x8*>(&L[cur][2][off]);
            bf16x8 bl = *reinterpret_cast<const bf16x8*>(&L[cur][3][off]);
#pragma unroll
            for (int mi = 0; mi < 4; ++mi) {
                acc[mi][ni] = __builtin_amdgcn_mfma_f32_16x16x32_bf16(ah[mi], bh, acc[mi][ni], 0, 0, 0);
                acc[mi][ni] = __builtin_amdgcn_mfma_f32_16x16x32_bf16(ah[mi], bl, acc[mi][ni], 0, 0, 0);
                acc[mi][ni] = __builtin_amdgcn_mfma_f32_16x16x32_bf16(al[mi], bh, acc[mi][ni], 0, 0, 0);
            }
        }
        __builtin_amdgcn_s_setprio(0);

        // drain own prefetch (issued ~48 MFMAs ago -> mostly landed), then
        // one barrier: all waves done reading L[cur] & staging L[cur^1]
        asm volatile("s_waitcnt vmcnt(0)" ::: "memory");
        __builtin_amdgcn_sched_barrier(0);
        __builtin_amdgcn_s_barrier();
        __builtin_amdgcn_sched_barrier(0);
    }

    // C/D layout: col = lane&15, row = (lane>>4)*4 + reg   [m89-verified]
    if (mode == 0) {
#pragma unroll
        for (int mi = 0; mi < 4; ++mi)
#pragma unroll
            for (int ni = 0; ni < 4; ++ni) {
                const int col  = n0 + wcol + ni * 16 + lr;
                const int tsel = col >> 9;
                const int h    = (col >> 5) & 15;
                const int dd   = col & 31;
#pragma unroll
                for (int reg = 0; reg < 4; ++reg) {
                    const int row = m0 + wrow + mi * 16 + lg * 4 + reg;
                    const int b = row >> 6, n = row & 63;
                    qkv_out[((((size_t)tsel * B_WIN + b) * H_HEADS + h) * N_TOK + n) * D_HEAD + dd]
                        = acc[mi][ni][reg];
                }
            }
    } else {
#pragma unroll
        for (int mi = 0; mi < 4; ++mi)
#pragma unroll
            for (int ni = 0; ni < 4; ++ni) {
                const int col = n0 + wcol + ni * 16 + lr;
                const float pb = bias[col];
#pragma unroll
                for (int reg = 0; reg < 4; ++reg) {
                    const int row = m0 + wrow + mi * 16 + lg * 4 + reg;
                    out[(size_t)row * Ncols_out + col] = acc[mi][ni][reg] + pb;
                }
            }
    }
}

// ---------------------------------------------------------------------------
// Kernel 2: per-(b,h) window attention; av emitted pre-split bf16 in TILED
// layout (feeds proj GEMM staging directly)
// ---------------------------------------------------------------------------
__global__ __launch_bounds__(256) void attn_kernel(
    const float* __restrict__ qkv,        // [3][B][H][N][D]
    const float* __restrict__ bias_table, // [(2ws-1)^2][H]
    const int*   __restrict__ rel_index,  // [64][64]
    float* __restrict__ attn_map,         // [B][H][64][64]
    unsigned short* __restrict__ avh,     // tiled [M rows][512 k=h*32+dd]
    unsigned short* __restrict__ avl)
{
    __shared__ float qs[64][36];
    __shared__ float ks[64][36];
    __shared__ float vs[64][36];
    __shared__ float ps[64][65];

    const int bh = blockIdx.x;
    const int b  = bh >> 4;
    const int h  = bh & 15;
    const int t  = threadIdx.x;

    const size_t plane = (size_t)B_WIN * H_HEADS * N_TOK * D_HEAD;
    const size_t base  = (size_t)bh * (N_TOK * D_HEAD);
    const float* qg = qkv + base;
    const float* kg = qkv + plane + base;
    const float* vg = qkv + 2 * plane + base;

    const int lrr = t >> 2;
    const int lc  = (t & 3) * 8;
    {
        float4 x0 = *reinterpret_cast<const float4*>(&qg[lrr * 32 + lc]);
        float4 x1 = *reinterpret_cast<const float4*>(&qg[lrr * 32 + lc + 4]);
        *reinterpret_cast<float4*>(&qs[lrr][lc])     = x0;
        *reinterpret_cast<float4*>(&qs[lrr][lc + 4]) = x1;
        float4 y0 = *reinterpret_cast<const float4*>(&kg[lrr * 32 + lc]);
        float4 y1 = *reinterpret_cast<const float4*>(&kg[lrr * 32 + lc + 4]);
        *reinterpret_cast<float4*>(&ks[lrr][lc])     = y0;
        *reinterpret_cast<float4*>(&ks[lrr][lc + 4]) = y1;
        float4 z0 = *reinterpret_cast<const float4*>(&vg[lrr * 32 + lc]);
        float4 z1 = *reinterpret_cast<const float4*>(&vg[lrr * 32 + lc + 4]);
        *reinterpret_cast<float4*>(&vs[lrr][lc])     = z0;
        *reinterpret_cast<float4*>(&vs[lrr][lc + 4]) = z1;
    }
    __syncthreads();

    const int r  = t >> 2;
    const int c0 = (t & 3) * 16;

    float qr[32];
#pragma unroll
    for (int u = 0; u < 8; ++u) {
        float4 qf = *reinterpret_cast<const float4*>(&qs[r][u * 4]);
        qr[u * 4 + 0] = qf.x; qr[u * 4 + 1] = qf.y;
        qr[u * 4 + 2] = qf.z; qr[u * 4 + 3] = qf.w;
    }

    const float scale = 0.1767766952966369f;  // 32^-0.5
    float p[16];
#pragma unroll
    for (int j = 0; j < 16; ++j) {
        const int c = c0 + j;
        float s = 0.f;
#pragma unroll
        for (int kk = 0; kk < 32; kk += 4) {
            float4 kf = *reinterpret_cast<const float4*>(&ks[c][kk]);
            s = fmaf(qr[kk + 0], kf.x, s);
            s = fmaf(qr[kk + 1], kf.y, s);
            s = fmaf(qr[kk + 2], kf.z, s);
            s = fmaf(qr[kk + 3], kf.w, s);
        }
        p[j] = fmaf(s, scale, bias_table[rel_index[(r << 6) + c] * H_HEADS + h]);
    }

    float mx = p[0];
#pragma unroll
    for (int j = 1; j < 16; ++j) mx = fmaxf(mx, p[j]);
    mx = fmaxf(mx, __shfl_xor(mx, 1));
    mx = fmaxf(mx, __shfl_xor(mx, 2));
    float sum = 0.f;
#pragma unroll
    for (int j = 0; j < 16; ++j) { p[j] = __expf(p[j] - mx); sum += p[j]; }
    sum += __shfl_xor(sum, 1);
    sum += __shfl_xor(sum, 2);
    const float inv = 1.0f / sum;
#pragma unroll
    for (int j = 0; j < 16; ++j) p[j] *= inv;

#pragma unroll
    for (int j = 0; j < 16; ++j) ps[r][c0 + j] = p[j];

    {
        size_t ab = ((size_t)bh * 64 + r) * 64 + c0;
        *reinterpret_cast<float4*>(&attn_map[ab + 0])  = make_float4(p[0],  p[1],  p[2],  p[3]);
        *reinterpret_cast<float4*>(&attn_map[ab + 4])  = make_float4(p[4],  p[5],  p[6],  p[7]);
        *reinterpret_cast<float4*>(&attn_map[ab + 8])  = make_float4(p[8],  p[9],  p[10], p[11]);
        *reinterpret_cast<float4*>(&attn_map[ab + 12]) = make_float4(p[12], p[13], p[14], p[15]);
    }
    __syncthreads();

    const int dd0 = (t & 3) * 8;
    float acc[8];
#pragma unroll
    for (int u = 0; u < 8; ++u) acc[u] = 0.f;
#pragma unroll 8
    for (int j = 0; j < 64; ++j) {
        const float pv = ps[r][j];
        float4 v0 = *reinterpret_cast<const float4*>(&vs[j][dd0]);
        float4 v1 = *reinterpret_cast<const float4*>(&vs[j][dd0 + 4]);
        acc[0] = fmaf(pv, v0.x, acc[0]);
        acc[1] = fmaf(pv, v0.y, acc[1]);
        acc[2] = fmaf(pv, v0.z, acc[2]);
        acc[3] = fmaf(pv, v0.w, acc[3]);
        acc[4] = fmaf(pv, v1.x, acc[4]);
        acc[5] = fmaf(pv, v1.y, acc[5]);
        acc[6] = fmaf(pv, v1.z, acc[6]);
        acc[7] = fmaf(pv, v1.w, acc[7]);
    }
    // tiled-layout write: row = b*64+r -> mb=b>>1, rloc=(b&1)*64+r; kt=h; s=t&3
    u16x8 hv, lv;
#pragma unroll
    for (int u = 0; u < 8; ++u) {
        unsigned short hh = f2bf_rn(acc[u]);
        hv[u] = hh;
        lv[u] = f2bf_rn(acc[u] - bf2f(hh));
    }
    size_t o = (size_t)(b >> 1) * 65536 + (size_t)h * 4096
             + (size_t)(t & 3) * 1024 + (size_t)((b & 1) * 64 + r) * 8;
    *reinterpret_cast<u16x8*>(&avh[o]) = hv;
    *reinterpret_cast<u16x8*>(&avl[o]) = lv;
}

// ---------------------------------------------------------------------------
extern "C" void kernel_launch(void* const* d_in, const int* in_sizes, int n_in,
                              void* d_out, int out_size, void* d_ws, size_t ws_size,
                              hipStream_t stream) {
    const float* x          = (const float*)d_in[0];
    const float* qkv_w      = (const float*)d_in[1];
    const float* proj_w     = (const float*)d_in[2];
    const float* proj_b     = (const float*)d_in[3];
    const float* bias_table = (const float*)d_in[4];
    const int*   rel_index  = (const int*)d_in[5];

    float* out      = (float*)d_out;                           // [131072][512]
    float* attn_map = (float*)d_out + (size_t)M_ROWS * C_DIM;  // [B][H][64][64]

    // d_ws (exactly 1 GiB): Xh | Xl (tiled bf16) | qkv fp32
    // avh/avl alias Xh/Xl (dead after QKV GEMM).
    unsigned short* Xh  = (unsigned short*)d_ws;
    unsigned short* Xl  = Xh + (size_t)M_ROWS * 512;
    float*          qkv = (float*)(Xl + (size_t)M_ROWS * 512);
    unsigned short* avh = Xh;
    unsigned short* avl = Xl;

    // qkv_w split parks in attn_map region of d_out (dead until attn
    // overwrites it). proj_w split parks at qkv head (dead after attn).
    unsigned short* qwTh = (unsigned short*)attn_map;
    unsigned short* qwTl = qwTh + (size_t)1536 * 512;
    unsigned short* pwTh = (unsigned short*)qkv;
    unsigned short* pwTl = pwTh + (size_t)512 * 512;

    xsplit_kernel<<<M_ROWS * 512 / 2048, 256, 0, stream>>>(x, Xh, Xl);
    wsplit_kernel<<<384, 256, 0, stream>>>(qkv_w, qwTh, qwTl, 1536);
    gemm_mfma_kernel<<<dim3(12, 1024), 256, 0, stream>>>(
        Xh, Xl, qwTh, qwTl, 0, qkv, nullptr, nullptr, 1536, 12);
    attn_kernel<<<B_WIN * H_HEADS, 256, 0, stream>>>(
        qkv, bias_table, rel_index, attn_map, avh, avl);
    wsplit_kernel<<<128, 256, 0, stream>>>(proj_w, pwTh, pwTl, 512);
    gemm_mfma_kernel<<<dim3(4, 1024), 256, 0, stream>>>(
        avh, avl, pwTh, pwTl, 1, nullptr, proj_b, out, 512, 4);
}

// Round 6
// 1261.393 us; speedup vs baseline: 1.5679x; 1.2209x over previous
//
#include <hip/hip_runtime.h>
#include <cstdint>
#include <cstddef>

// Problem constants (Swin window attention)
#define B_WIN   2048
#define N_TOK   64
#define C_DIM   512
#define H_HEADS 16
#define D_HEAD  32
#define K_DIM   512
#define M_ROWS  (B_WIN * 64)   // 131072

// Tiled operand layout for GEMM staging (bf16):
//   T[mb][kt][s][r][e]  mb=row>>7, kt=k>>5, s=(k>>3)&3, r=row&127, e=k&7
//   flat elem = mb*65536 + kt*4096 + s*1024 + r*8 + e

typedef __bf16 bf16x8 __attribute__((ext_vector_type(8)));
typedef float  f32x4  __attribute__((ext_vector_type(4)));
typedef unsigned short u16x8 __attribute__((ext_vector_type(8)));

__device__ __forceinline__ unsigned short f2bf_rn(float f) {
    unsigned u = __float_as_uint(f);
    u += 0x7fffu + ((u >> 16) & 1u);
    return (unsigned short)(u >> 16);
}
__device__ __forceinline__ float bf2f(unsigned short h) {
    return __uint_as_float(((unsigned)h) << 16);
}
__device__ __forceinline__ void gload16(const void* g, void* l) {
    __builtin_amdgcn_global_load_lds(
        (const __attribute__((address_space(1))) void*)g,
        (__attribute__((address_space(3))) void*)l,
        16, 0, 0);
}

// ---------------------------------------------------------------------------
// bias_expand: bias_hn[h][i][j] = table[rel[i][j]][h]   (65536 floats)
// ---------------------------------------------------------------------------
__global__ void bias_expand_kernel(const float* __restrict__ bias_table,
                                   const int* __restrict__ rel_index,
                                   float* __restrict__ bias_hn) {
    int tid = blockIdx.x * 256 + threadIdx.x;
    int h  = tid >> 12;
    int ij = tid & 4095;
    bias_hn[tid] = bias_table[rel_index[ij] * H_HEADS + h];
}

// ---------------------------------------------------------------------------
// xsplit: x [M][512] fp32 -> Xh/Xl bf16 hi/lo in TILED layout.
// ---------------------------------------------------------------------------
__global__ __launch_bounds__(256) void xsplit_kernel(
    const float* __restrict__ x,
    unsigned short* __restrict__ Xh,
    unsigned short* __restrict__ Xl)
{
    size_t e8 = ((size_t)blockIdx.x * 256 + threadIdx.x) * 8;
    const int mb = (int)(e8 >> 16);
    const int w  = (int)(e8 & 65535);
    const int kt = w >> 12;
    const int s  = (w >> 10) & 3;
    const int r  = (w >> 3) & 127;
    const int m  = mb * 128 + r;
    const int k  = kt * 32 + s * 8;
    const float* src = &x[(size_t)m * 512 + k];
    float4 f0 = *reinterpret_cast<const float4*>(src);
    float4 f1 = *reinterpret_cast<const float4*>(src + 4);
    float fv[8] = {f0.x, f0.y, f0.z, f0.w, f1.x, f1.y, f1.z, f1.w};
    u16x8 hi, lo;
#pragma unroll
    for (int j = 0; j < 8; ++j) {
        unsigned short h = f2bf_rn(fv[j]);
        hi[j] = h;
        lo[j] = f2bf_rn(fv[j] - bf2f(h));
    }
    *reinterpret_cast<u16x8*>(&Xh[e8]) = hi;
    *reinterpret_cast<u16x8*>(&Xl[e8]) = lo;
}

// ---------------------------------------------------------------------------
// wsplit: w[512 k][Ncols n] -> wTh/wTl (rows=n, 512 k) in TILED layout
// ---------------------------------------------------------------------------
__global__ __launch_bounds__(256) void wsplit_kernel(
    const float* __restrict__ w,
    unsigned short* __restrict__ wTh,
    unsigned short* __restrict__ wTl,
    int Ncols)
{
    size_t e8 = ((size_t)blockIdx.x * 256 + threadIdx.x) * 8;
    const int mb = (int)(e8 >> 16);
    const int ww = (int)(e8 & 65535);
    const int kt = ww >> 12;
    const int s  = (ww >> 10) & 3;
    const int r  = (ww >> 3) & 127;
    const int n  = mb * 128 + r;
    const int k  = kt * 32 + s * 8;
    u16x8 hi, lo;
#pragma unroll
    for (int j = 0; j < 8; ++j) {
        float v = w[(size_t)(k + j) * Ncols + n];
        unsigned short h = f2bf_rn(v);
        hi[j] = h;
        lo[j] = f2bf_rn(v - bf2f(h));
    }
    *reinterpret_cast<u16x8*>(&wTh[e8]) = hi;
    *reinterpret_cast<u16x8*>(&wTl[e8]) = lo;
}

// ---------------------------------------------------------------------------
// bf16x3-split MFMA GEMM (unchanged from R5 — proven)
// ---------------------------------------------------------------------------
__global__ __launch_bounds__(256) void gemm_mfma_kernel(
    const unsigned short* __restrict__ ATh,
    const unsigned short* __restrict__ ATl,
    const unsigned short* __restrict__ BTh,
    const unsigned short* __restrict__ BTl,
    int mode,
    float* __restrict__ qkv_out,
    const float* __restrict__ bias,
    float* __restrict__ out,
    int Ncols_out,
    int nb_grid)
{
    __shared__ __align__(16) unsigned short L[2][4][4096];

    const int t    = threadIdx.x;
    const int lane = t & 63;
    const int wave = t >> 6;
    const int lg   = lane >> 4;
    const int lr   = lane & 15;
    const int wrow = (wave >> 1) * 64;
    const int wcol = (wave & 1) * 64;

    const int lin = blockIdx.x + gridDim.x * blockIdx.y;
    const int nwg = gridDim.x * gridDim.y;
    const int cpx = nwg >> 3;
    const int swz = (lin & 7) * cpx + (lin >> 3);
    const int m0  = (swz / nb_grid) * 128;
    const int n0  = (swz % nb_grid) * 128;
    const size_t tbA = (size_t)(m0 >> 7) * 16 * 4096;
    const size_t tbB = (size_t)(n0 >> 7) * 16 * 4096;

    f32x4 acc[4][4];
#pragma unroll
    for (int i = 0; i < 4; ++i)
#pragma unroll
        for (int j = 0; j < 4; ++j) acc[i][j] = (f32x4){0.f, 0.f, 0.f, 0.f};

    auto stage = [&](int kt, int bi) {
        const size_t bA = tbA + (size_t)kt * 4096;
        const size_t bB = tbB + (size_t)kt * 4096;
#pragma unroll
        for (int i = 0; i < 2; ++i) {
            const int c = i * 256 + t;
            gload16(&ATh[bA + c * 8], &L[bi][0][c * 8]);
            gload16(&ATl[bA + c * 8], &L[bi][1][c * 8]);
            gload16(&BTh[bB + c * 8], &L[bi][2][c * 8]);
            gload16(&BTl[bB + c * 8], &L[bi][3][c * 8]);
        }
    };

    stage(0, 0);
    asm volatile("s_waitcnt vmcnt(0)" ::: "memory");
    __builtin_amdgcn_sched_barrier(0);
    __builtin_amdgcn_s_barrier();
    __builtin_amdgcn_sched_barrier(0);

#pragma unroll 2
    for (int ks = 0; ks < 16; ++ks) {
        const int cur = ks & 1;
        if (ks + 1 < 16) stage(ks + 1, cur ^ 1);

        bf16x8 ah[4], al[4];
#pragma unroll
        for (int mi = 0; mi < 4; ++mi) {
            const int off = lg * 1024 + (wrow + mi * 16 + lr) * 8;
            ah[mi] = *reinterpret_cast<const bf16x8*>(&L[cur][0][off]);
            al[mi] = *reinterpret_cast<const bf16x8*>(&L[cur][1][off]);
        }
        __builtin_amdgcn_s_setprio(1);
#pragma unroll
        for (int ni = 0; ni < 4; ++ni) {
            const int off = lg * 1024 + (wcol + ni * 16 + lr) * 8;
            bf16x8 bh = *reinterpret_cast<const bf16x8*>(&L[cur][2][off]);
            bf16x8 bl = *reinterpret_cast<const bf16x8*>(&L[cur][3][off]);
#pragma unroll
            for (int mi = 0; mi < 4; ++mi) {
                acc[mi][ni] = __builtin_amdgcn_mfma_f32_16x16x32_bf16(ah[mi], bh, acc[mi][ni], 0, 0, 0);
                acc[mi][ni] = __builtin_amdgcn_mfma_f32_16x16x32_bf16(ah[mi], bl, acc[mi][ni], 0, 0, 0);
                acc[mi][ni] = __builtin_amdgcn_mfma_f32_16x16x32_bf16(al[mi], bh, acc[mi][ni], 0, 0, 0);
            }
        }
        __builtin_amdgcn_s_setprio(0);

        asm volatile("s_waitcnt vmcnt(0)" ::: "memory");
        __builtin_amdgcn_sched_barrier(0);
        __builtin_amdgcn_s_barrier();
        __builtin_amdgcn_sched_barrier(0);
    }

    if (mode == 0) {
#pragma unroll
        for (int mi = 0; mi < 4; ++mi)
#pragma unroll
            for (int ni = 0; ni < 4; ++ni) {
                const int col  = n0 + wcol + ni * 16 + lr;
                const int tsel = col >> 9;
                const int h    = (col >> 5) & 15;
                const int dd   = col & 31;
#pragma unroll
                for (int reg = 0; reg < 4; ++reg) {
                    const int row = m0 + wrow + mi * 16 + lg * 4 + reg;
                    const int b = row >> 6, n = row & 63;
                    qkv_out[((((size_t)tsel * B_WIN + b) * H_HEADS + h) * N_TOK + n) * D_HEAD + dd]
                        = acc[mi][ni][reg];
                }
            }
    } else {
#pragma unroll
        for (int mi = 0; mi < 4; ++mi)
#pragma unroll
            for (int ni = 0; ni < 4; ++ni) {
                const int col = n0 + wcol + ni * 16 + lr;
                const float pb = bias[col];
#pragma unroll
                for (int reg = 0; reg < 4; ++reg) {
                    const int row = m0 + wrow + mi * 16 + lg * 4 + reg;
                    out[(size_t)row * Ncols_out + col] = acc[mi][ni][reg] + pb;
                }
            }
    }
}

// ---------------------------------------------------------------------------
// MFMA window attention: 1 block = (b,h), 4 waves. bf16x3-split QK^T and PV,
// softmax in C/D register layout (row-reduce = 4x shfl_xor over lane bits 0-3).
// LDS 29.7KB: region A {Qh,Ql,Kh,Kl [64][40]} reused as {Ph,Pl [64][72]};
// region B {VTh,VTl [32][72]}. Only 2 barriers (P exchange is intra-wave).
// ---------------------------------------------------------------------------
__global__ __launch_bounds__(256, 4) void attn_kernel(
    const float* __restrict__ qkv,        // [3][B][H][N][D]
    const float* __restrict__ bias_hn,    // [H][64][64]
    float* __restrict__ attn_map,         // [B][H][64][64]
    unsigned short* __restrict__ avh,     // tiled bf16 hi
    unsigned short* __restrict__ avl)     // tiled bf16 lo
{
    __shared__ __align__(16) unsigned short SM[14848];
    constexpr int QH = 0, QL = 2560, KH = 5120, KL = 7680;   // [64][40]
    constexpr int PH = 0, PL = 4608;                         // [64][72]
    constexpr int VTH = 10240, VTL = 12544;                  // [32][72]

    const int bh   = blockIdx.x;
    const int b    = bh >> 4;
    const int h    = bh & 15;
    const int t    = threadIdx.x;
    const int lane = t & 63;
    const int wv   = t >> 6;
    const int lg   = lane >> 4;
    const int lr   = lane & 15;

    const size_t plane = (size_t)B_WIN * H_HEADS * N_TOK * D_HEAD;
    const size_t base  = (size_t)bh * (N_TOK * D_HEAD);
    const float* qg = qkv + base;
    const float* kg = qkv + plane + base;
    const float* vg = qkv + 2 * plane + base;

    // ---- load q,k (hi/lo -> LDS rows) and v (hi/lo -> LDS transposed) ----
    {
        const int r  = t >> 2;
        const int c0 = (t & 3) * 8;
        float4 a0 = *reinterpret_cast<const float4*>(&qg[r * 32 + c0]);
        float4 a1 = *reinterpret_cast<const float4*>(&qg[r * 32 + c0 + 4]);
        float qv[8] = {a0.x, a0.y, a0.z, a0.w, a1.x, a1.y, a1.z, a1.w};
        u16x8 hi, lo;
#pragma unroll
        for (int j = 0; j < 8; ++j) {
            unsigned short hh = f2bf_rn(qv[j]);
            hi[j] = hh; lo[j] = f2bf_rn(qv[j] - bf2f(hh));
        }
        *reinterpret_cast<u16x8*>(&SM[QH + r * 40 + c0]) = hi;
        *reinterpret_cast<u16x8*>(&SM[QL + r * 40 + c0]) = lo;

        float4 k0 = *reinterpret_cast<const float4*>(&kg[r * 32 + c0]);
        float4 k1 = *reinterpret_cast<const float4*>(&kg[r * 32 + c0 + 4]);
        float kv[8] = {k0.x, k0.y, k0.z, k0.w, k1.x, k1.y, k1.z, k1.w};
#pragma unroll
        for (int j = 0; j < 8; ++j) {
            unsigned short hh = f2bf_rn(kv[j]);
            hi[j] = hh; lo[j] = f2bf_rn(kv[j] - bf2f(hh));
        }
        *reinterpret_cast<u16x8*>(&SM[KH + r * 40 + c0]) = hi;
        *reinterpret_cast<u16x8*>(&SM[KL + r * 40 + c0]) = lo;

        float4 v0 = *reinterpret_cast<const float4*>(&vg[r * 32 + c0]);
        float4 v1 = *reinterpret_cast<const float4*>(&vg[r * 32 + c0 + 4]);
        float vv[8] = {v0.x, v0.y, v0.z, v0.w, v1.x, v1.y, v1.z, v1.w};
#pragma unroll
        for (int u = 0; u < 8; ++u) {
            const int d = c0 + u;
            unsigned short hh = f2bf_rn(vv[u]);
            SM[VTH + d * 72 + r] = hh;
            SM[VTL + d * 72 + r] = f2bf_rn(vv[u] - bf2f(hh));
        }
    }
    __syncthreads();

    // ---- bias preload (coalesced 64B rows from bias_hn) ----
    float bias[4][4];
#pragma unroll
    for (int reg = 0; reg < 4; ++reg)
#pragma unroll
        for (int c = 0; c < 4; ++c)
            bias[reg][c] = bias_hn[(h << 12) + ((wv * 16 + lg * 4 + reg) << 6) + c * 16 + lr];

    // ---- QK^T: wave owns rows 16wv..16wv+15, S[c] = 16x16 col-tile ----
    const int ar = wv * 16 + lr;
    bf16x8 qa_h = *reinterpret_cast<const bf16x8*>(&SM[QH + ar * 40 + lg * 8]);
    bf16x8 qa_l = *reinterpret_cast<const bf16x8*>(&SM[QL + ar * 40 + lg * 8]);
    f32x4 S[4];
#pragma unroll
    for (int c = 0; c < 4; ++c) {
        const int br = c * 16 + lr;
        bf16x8 kb_h = *reinterpret_cast<const bf16x8*>(&SM[KH + br * 40 + lg * 8]);
        bf16x8 kb_l = *reinterpret_cast<const bf16x8*>(&SM[KL + br * 40 + lg * 8]);
        f32x4 s = (f32x4){0.f, 0.f, 0.f, 0.f};
        s = __builtin_amdgcn_mfma_f32_16x16x32_bf16(qa_h, kb_h, s, 0, 0, 0);
        s = __builtin_amdgcn_mfma_f32_16x16x32_bf16(qa_h, kb_l, s, 0, 0, 0);
        s = __builtin_amdgcn_mfma_f32_16x16x32_bf16(qa_l, kb_h, s, 0, 0, 0);
        S[c] = s;
    }
    __syncthreads();   // Q/K region dead -> reusable for P

    // ---- scale + bias + softmax, rows R = 16wv + 4lg + reg ----
    const float scale = 0.1767766952966369f;  // 32^-0.5
    float p[4][4], mx[4], sm[4];
#pragma unroll
    for (int reg = 0; reg < 4; ++reg) mx[reg] = -1e30f;
#pragma unroll
    for (int reg = 0; reg < 4; ++reg)
#pragma unroll
        for (int c = 0; c < 4; ++c) {
            float s = fmaf(S[c][reg], scale, bias[reg][c]);
            p[reg][c] = s;
            mx[reg] = fmaxf(mx[reg], s);
        }
#pragma unroll
    for (int reg = 0; reg < 4; ++reg) {
        mx[reg] = fmaxf(mx[reg], __shfl_xor(mx[reg], 1));
        mx[reg] = fmaxf(mx[reg], __shfl_xor(mx[reg], 2));
        mx[reg] = fmaxf(mx[reg], __shfl_xor(mx[reg], 4));
        mx[reg] = fmaxf(mx[reg], __shfl_xor(mx[reg], 8));
        sm[reg] = 0.f;
    }
#pragma unroll
    for (int reg = 0; reg < 4; ++reg)
#pragma unroll
        for (int c = 0; c < 4; ++c) {
            float e = __expf(p[reg][c] - mx[reg]);
            p[reg][c] = e;
            sm[reg] += e;
        }
#pragma unroll
    for (int reg = 0; reg < 4; ++reg) {
        sm[reg] += __shfl_xor(sm[reg], 1);
        sm[reg] += __shfl_xor(sm[reg], 2);
        sm[reg] += __shfl_xor(sm[reg], 4);
        sm[reg] += __shfl_xor(sm[reg], 8);
        const float inv = 1.0f / sm[reg];
#pragma unroll
        for (int c = 0; c < 4; ++c) p[reg][c] *= inv;
    }

    // ---- emit attn_map + P (hi/lo bf16, pair-packed u32) to LDS ----
    const size_t amb = (size_t)bh * 4096;
#pragma unroll
    for (int reg = 0; reg < 4; ++reg) {
        const int R = wv * 16 + lg * 4 + reg;
#pragma unroll
        for (int c = 0; c < 4; ++c) {
            const int C = c * 16 + lr;
            const float own = p[reg][c];
            attn_map[amb + R * 64 + C] = own;
            const float mate = __shfl_xor(own, 1);
            if (!(lr & 1)) {
                unsigned short h0 = f2bf_rn(own);
                unsigned short l0 = f2bf_rn(own - bf2f(h0));
                unsigned short h1 = f2bf_rn(mate);
                unsigned short l1 = f2bf_rn(mate - bf2f(h1));
                *reinterpret_cast<unsigned*>(&SM[PH + R * 72 + C]) =
                    (unsigned)h0 | ((unsigned)h1 << 16);
                *reinterpret_cast<unsigned*>(&SM[PL + R * 72 + C]) =
                    (unsigned)l0 | ((unsigned)l1 << 16);
            }
        }
    }
    // no barrier: wave w's PV a-frags read rows 16wv..16wv+15 = its own writes

    // ---- PV: O[n] = P[16 rows][64 k] x V[64 k][16n..16n+15] ----
    f32x4 O[2];
    O[0] = (f32x4){0.f, 0.f, 0.f, 0.f};
    O[1] = (f32x4){0.f, 0.f, 0.f, 0.f};
#pragma unroll
    for (int kk = 0; kk < 2; ++kk) {
        const int pr = wv * 16 + lr;
        bf16x8 pa_h = *reinterpret_cast<const bf16x8*>(&SM[PH + pr * 72 + kk * 32 + lg * 8]);
        bf16x8 pa_l = *reinterpret_cast<const bf16x8*>(&SM[PL + pr * 72 + kk * 32 + lg * 8]);
#pragma unroll
        for (int n = 0; n < 2; ++n) {
            const int vr = n * 16 + lr;
            bf16x8 vb_h = *reinterpret_cast<const bf16x8*>(&SM[VTH + vr * 72 + kk * 32 + lg * 8]);
            bf16x8 vb_l = *reinterpret_cast<const bf16x8*>(&SM[VTL + vr * 72 + kk * 32 + lg * 8]);
            O[n] = __builtin_amdgcn_mfma_f32_16x16x32_bf16(pa_h, vb_h, O[n], 0, 0, 0);
            O[n] = __builtin_amdgcn_mfma_f32_16x16x32_bf16(pa_h, vb_l, O[n], 0, 0, 0);
            O[n] = __builtin_amdgcn_mfma_f32_16x16x32_bf16(pa_l, vb_h, O[n], 0, 0, 0);
        }
    }

    // ---- av store: tiled layout [mb][kt=h][s][r][e], hi/lo bf16 ----
    const int mb = b >> 1;
#pragma unroll
    for (int n = 0; n < 2; ++n)
#pragma unroll
        for (int reg = 0; reg < 4; ++reg) {
            const int R  = wv * 16 + lg * 4 + reg;
            const int d  = n * 16 + lr;
            const int rl = (b & 1) * 64 + R;
            const float o = O[n][reg];
            unsigned short oh = f2bf_rn(o);
            unsigned short ol = f2bf_rn(o - bf2f(oh));
            size_t off = (size_t)mb * 65536 + (size_t)h * 4096
                       + (size_t)(d >> 3) * 1024 + (size_t)rl * 8 + (d & 7);
            avh[off] = oh;
            avl[off] = ol;
        }
}

// ---------------------------------------------------------------------------
extern "C" void kernel_launch(void* const* d_in, const int* in_sizes, int n_in,
                              void* d_out, int out_size, void* d_ws, size_t ws_size,
                              hipStream_t stream) {
    const float* x          = (const float*)d_in[0];
    const float* qkv_w      = (const float*)d_in[1];
    const float* proj_w     = (const float*)d_in[2];
    const float* proj_b     = (const float*)d_in[3];
    const float* bias_table = (const float*)d_in[4];
    const int*   rel_index  = (const int*)d_in[5];

    float* out      = (float*)d_out;                           // [131072][512]
    float* attn_map = (float*)d_out + (size_t)M_ROWS * C_DIM;  // [B][H][64][64]

    // d_ws: Xh | Xl (tiled bf16) | qkv fp32   (~1.074 GB, same as R1-R5)
    unsigned short* Xh  = (unsigned short*)d_ws;
    unsigned short* Xl  = Xh + (size_t)M_ROWS * 512;
    float*          qkv = (float*)(Xl + (size_t)M_ROWS * 512);
    unsigned short* avh = Xh;   // alias: dead after QKV GEMM
    unsigned short* avl = Xl;

    // parking: qkv_w split -> attn_map region (dead until attn overwrites);
    // proj_w split -> qkv head (dead after attn); bias_hn -> out head
    // (out written only by the final proj GEMM).
    unsigned short* qwTh = (unsigned short*)attn_map;
    unsigned short* qwTl = qwTh + (size_t)1536 * 512;
    unsigned short* pwTh = (unsigned short*)qkv;
    unsigned short* pwTl = pwTh + (size_t)512 * 512;
    float* bias_hn = out;   // 65536 floats at head of out region

    bias_expand_kernel<<<256, 256, 0, stream>>>(bias_table, rel_index, bias_hn);
    xsplit_kernel<<<M_ROWS * 512 / 2048, 256, 0, stream>>>(x, Xh, Xl);
    wsplit_kernel<<<384, 256, 0, stream>>>(qkv_w, qwTh, qwTl, 1536);
    gemm_mfma_kernel<<<dim3(12, 1024), 256, 0, stream>>>(
        Xh, Xl, qwTh, qwTl, 0, qkv, nullptr, nullptr, 1536, 12);
    attn_kernel<<<B_WIN * H_HEADS, 256, 0, stream>>>(
        qkv, bias_hn, attn_map, avh, avl);
    wsplit_kernel<<<128, 256, 0, stream>>>(proj_w, pwTh, pwTl, 512);
    gemm_mfma_kernel<<<dim3(4, 1024), 256, 0, stream>>>(
        avh, avl, pwTh, pwTl, 1, nullptr, proj_b, out, 512, 4);
}

// Round 7
// 1228.095 us; speedup vs baseline: 1.6104x; 1.0271x over previous
//
#include <hip/hip_runtime.h>
#include <cstdint>
#include <cstddef>

// Problem constants (Swin window attention)
#define B_WIN   2048
#define N_TOK   64
#define C_DIM   512
#define H_HEADS 16
#define D_HEAD  32
#define K_DIM   512
#define M_ROWS  (B_WIN * 64)   // 131072

// Tiled operand layout for GEMM staging (bf16):
//   T[mb][kt][s][r][e]  mb=row>>7, kt=k>>5, s=(k>>3)&3, r=row&127, e=k&7
//   flat elem = mb*65536 + kt*4096 + s*1024 + r*8 + e

typedef __bf16 bf16x8 __attribute__((ext_vector_type(8)));
typedef float  f32x4  __attribute__((ext_vector_type(4)));
typedef unsigned short u16x8 __attribute__((ext_vector_type(8)));

__device__ __forceinline__ unsigned short f2bf_rn(float f) {
    unsigned u = __float_as_uint(f);
    u += 0x7fffu + ((u >> 16) & 1u);
    return (unsigned short)(u >> 16);
}
__device__ __forceinline__ float bf2f(unsigned short h) {
    return __uint_as_float(((unsigned)h) << 16);
}
__device__ __forceinline__ void gload16(const void* g, void* l) {
    __builtin_amdgcn_global_load_lds(
        (const __attribute__((address_space(1))) void*)g,
        (__attribute__((address_space(3))) void*)l,
        16, 0, 0);
}

// ---------------------------------------------------------------------------
// bias_expand: bias_hn[h][i][j] = table[rel[i][j]][h]   (65536 floats)
// ---------------------------------------------------------------------------
__global__ void bias_expand_kernel(const float* __restrict__ bias_table,
                                   const int* __restrict__ rel_index,
                                   float* __restrict__ bias_hn) {
    int tid = blockIdx.x * 256 + threadIdx.x;
    int h  = tid >> 12;
    int ij = tid & 4095;
    bias_hn[tid] = bias_table[rel_index[ij] * H_HEADS + h];
}

// ---------------------------------------------------------------------------
// xsplit: x [M][512] fp32 -> Xh/Xl bf16 hi/lo in TILED layout.
// ---------------------------------------------------------------------------
__global__ __launch_bounds__(256) void xsplit_kernel(
    const float* __restrict__ x,
    unsigned short* __restrict__ Xh,
    unsigned short* __restrict__ Xl)
{
    size_t e8 = ((size_t)blockIdx.x * 256 + threadIdx.x) * 8;
    const int mb = (int)(e8 >> 16);
    const int w  = (int)(e8 & 65535);
    const int kt = w >> 12;
    const int s  = (w >> 10) & 3;
    const int r  = (w >> 3) & 127;
    const int m  = mb * 128 + r;
    const int k  = kt * 32 + s * 8;
    const float* src = &x[(size_t)m * 512 + k];
    float4 f0 = *reinterpret_cast<const float4*>(src);
    float4 f1 = *reinterpret_cast<const float4*>(src + 4);
    float fv[8] = {f0.x, f0.y, f0.z, f0.w, f1.x, f1.y, f1.z, f1.w};
    u16x8 hi, lo;
#pragma unroll
    for (int j = 0; j < 8; ++j) {
        unsigned short h = f2bf_rn(fv[j]);
        hi[j] = h;
        lo[j] = f2bf_rn(fv[j] - bf2f(h));
    }
    *reinterpret_cast<u16x8*>(&Xh[e8]) = hi;
    *reinterpret_cast<u16x8*>(&Xl[e8]) = lo;
}

// ---------------------------------------------------------------------------
// wsplit: w[512 k][Ncols n] -> wTh/wTl (rows=n, 512 k) in TILED layout
// ---------------------------------------------------------------------------
__global__ __launch_bounds__(256) void wsplit_kernel(
    const float* __restrict__ w,
    unsigned short* __restrict__ wTh,
    unsigned short* __restrict__ wTl,
    int Ncols)
{
    size_t e8 = ((size_t)blockIdx.x * 256 + threadIdx.x) * 8;
    const int mb = (int)(e8 >> 16);
    const int ww = (int)(e8 & 65535);
    const int kt = ww >> 12;
    const int s  = (ww >> 10) & 3;
    const int r  = (ww >> 3) & 127;
    const int n  = mb * 128 + r;
    const int k  = kt * 32 + s * 8;
    u16x8 hi, lo;
#pragma unroll
    for (int j = 0; j < 8; ++j) {
        float v = w[(size_t)(k + j) * Ncols + n];
        unsigned short h = f2bf_rn(v);
        hi[j] = h;
        lo[j] = f2bf_rn(v - bf2f(h));
    }
    *reinterpret_cast<u16x8*>(&wTh[e8]) = hi;
    *reinterpret_cast<u16x8*>(&wTl[e8]) = lo;
}

// ---------------------------------------------------------------------------
// bf16x3-split MFMA GEMM, 128x128 tile, BK=32, 16 steps.
// NOW 8 waves (512 thr): wave-tile 32x64, acc[2][4], 24 MFMA/wave/step.
// Same 64KB double-buffered LDS -> 2 blocks/CU -> 4 waves/SIMD (TLP to hide
// the vmcnt drain; two independent blocks interleave barrier phases).
// ---------------------------------------------------------------------------
__global__ __launch_bounds__(512, 4) void gemm_mfma_kernel(
    const unsigned short* __restrict__ ATh,
    const unsigned short* __restrict__ ATl,
    const unsigned short* __restrict__ BTh,
    const unsigned short* __restrict__ BTl,
    int mode,
    float* __restrict__ qkv_out,
    const float* __restrict__ bias,
    float* __restrict__ out,
    int Ncols_out,
    int nb_grid)
{
    __shared__ __align__(16) unsigned short L[2][4][4096];  // op: Ah Al Bh Bl

    const int t    = threadIdx.x;
    const int lane = t & 63;
    const int wave = t >> 6;         // 0..7
    const int lg   = lane >> 4;      // k-octet 0..3
    const int lr   = lane & 15;      // row within fragment
    const int wrow = (wave >> 1) * 32;   // 0,32,64,96
    const int wcol = (wave & 1) * 64;    // 0,64

    const int lin = blockIdx.x + gridDim.x * blockIdx.y;
    const int nwg = gridDim.x * gridDim.y;
    const int cpx = nwg >> 3;
    const int swz = (lin & 7) * cpx + (lin >> 3);
    const int m0  = (swz / nb_grid) * 128;
    const int n0  = (swz % nb_grid) * 128;
    const size_t tbA = (size_t)(m0 >> 7) * 16 * 4096;
    const size_t tbB = (size_t)(n0 >> 7) * 16 * 4096;

    f32x4 acc[2][4];
#pragma unroll
    for (int i = 0; i < 2; ++i)
#pragma unroll
        for (int j = 0; j < 4; ++j) acc[i][j] = (f32x4){0.f, 0.f, 0.f, 0.f};

    // stage all 4 operand tiles for K-step kt into buffer bi (4 gloads/thread)
    auto stage = [&](int kt, int bi) {
        const size_t bA = tbA + (size_t)kt * 4096 + (size_t)t * 8;
        const size_t bB = tbB + (size_t)kt * 4096 + (size_t)t * 8;
        gload16(&ATh[bA], &L[bi][0][t * 8]);
        gload16(&ATl[bA], &L[bi][1][t * 8]);
        gload16(&BTh[bB], &L[bi][2][t * 8]);
        gload16(&BTl[bB], &L[bi][3][t * 8]);
    };

    stage(0, 0);
    asm volatile("s_waitcnt vmcnt(0)" ::: "memory");
    __builtin_amdgcn_sched_barrier(0);
    __builtin_amdgcn_s_barrier();
    __builtin_amdgcn_sched_barrier(0);

#pragma unroll 2
    for (int ks = 0; ks < 16; ++ks) {
        const int cur = ks & 1;
        if (ks + 1 < 16) stage(ks + 1, cur ^ 1);

        bf16x8 ah[2], al[2];
#pragma unroll
        for (int mi = 0; mi < 2; ++mi) {
            const int off = lg * 1024 + (wrow + mi * 16 + lr) * 8;
            ah[mi] = *reinterpret_cast<const bf16x8*>(&L[cur][0][off]);
            al[mi] = *reinterpret_cast<const bf16x8*>(&L[cur][1][off]);
        }
        __builtin_amdgcn_s_setprio(1);
#pragma unroll
        for (int ni = 0; ni < 4; ++ni) {
            const int off = lg * 1024 + (wcol + ni * 16 + lr) * 8;
            bf16x8 bh = *reinterpret_cast<const bf16x8*>(&L[cur][2][off]);
            bf16x8 bl = *reinterpret_cast<const bf16x8*>(&L[cur][3][off]);
#pragma unroll
            for (int mi = 0; mi < 2; ++mi) {
                acc[mi][ni] = __builtin_amdgcn_mfma_f32_16x16x32_bf16(ah[mi], bh, acc[mi][ni], 0, 0, 0);
                acc[mi][ni] = __builtin_amdgcn_mfma_f32_16x16x32_bf16(ah[mi], bl, acc[mi][ni], 0, 0, 0);
                acc[mi][ni] = __builtin_amdgcn_mfma_f32_16x16x32_bf16(al[mi], bh, acc[mi][ni], 0, 0, 0);
            }
        }
        __builtin_amdgcn_s_setprio(0);

        asm volatile("s_waitcnt vmcnt(0)" ::: "memory");
        __builtin_amdgcn_sched_barrier(0);
        __builtin_amdgcn_s_barrier();
        __builtin_amdgcn_sched_barrier(0);
    }

    // C/D layout: col = lane&15, row = (lane>>4)*4 + reg   [m89-verified]
    if (mode == 0) {
#pragma unroll
        for (int mi = 0; mi < 2; ++mi)
#pragma unroll
            for (int ni = 0; ni < 4; ++ni) {
                const int col  = n0 + wcol + ni * 16 + lr;
                const int tsel = col >> 9;
                const int h    = (col >> 5) & 15;
                const int dd   = col & 31;
#pragma unroll
                for (int reg = 0; reg < 4; ++reg) {
                    const int row = m0 + wrow + mi * 16 + lg * 4 + reg;
                    const int b = row >> 6, n = row & 63;
                    qkv_out[((((size_t)tsel * B_WIN + b) * H_HEADS + h) * N_TOK + n) * D_HEAD + dd]
                        = acc[mi][ni][reg];
                }
            }
    } else {
#pragma unroll
        for (int mi = 0; mi < 2; ++mi)
#pragma unroll
            for (int ni = 0; ni < 4; ++ni) {
                const int col = n0 + wcol + ni * 16 + lr;
                const float pb = bias[col];
#pragma unroll
                for (int reg = 0; reg < 4; ++reg) {
                    const int row = m0 + wrow + mi * 16 + lg * 4 + reg;
                    out[(size_t)row * Ncols_out + col] = acc[mi][ni][reg] + pb;
                }
            }
    }
}

// ---------------------------------------------------------------------------
// MFMA window attention (unchanged from R6 — proven)
// ---------------------------------------------------------------------------
__global__ __launch_bounds__(256, 4) void attn_kernel(
    const float* __restrict__ qkv,        // [3][B][H][N][D]
    const float* __restrict__ bias_hn,    // [H][64][64]
    float* __restrict__ attn_map,         // [B][H][64][64]
    unsigned short* __restrict__ avh,     // tiled bf16 hi
    unsigned short* __restrict__ avl)     // tiled bf16 lo
{
    __shared__ __align__(16) unsigned short SM[14848];
    constexpr int QH = 0, QL = 2560, KH = 5120, KL = 7680;   // [64][40]
    constexpr int PH = 0, PL = 4608;                         // [64][72]
    constexpr int VTH = 10240, VTL = 12544;                  // [32][72]

    const int bh   = blockIdx.x;
    const int b    = bh >> 4;
    const int h    = bh & 15;
    const int t    = threadIdx.x;
    const int lane = t & 63;
    const int wv   = t >> 6;
    const int lg   = lane >> 4;
    const int lr   = lane & 15;

    const size_t plane = (size_t)B_WIN * H_HEADS * N_TOK * D_HEAD;
    const size_t base  = (size_t)bh * (N_TOK * D_HEAD);
    const float* qg = qkv + base;
    const float* kg = qkv + plane + base;
    const float* vg = qkv + 2 * plane + base;

    {
        const int r  = t >> 2;
        const int c0 = (t & 3) * 8;
        float4 a0 = *reinterpret_cast<const float4*>(&qg[r * 32 + c0]);
        float4 a1 = *reinterpret_cast<const float4*>(&qg[r * 32 + c0 + 4]);
        float qv[8] = {a0.x, a0.y, a0.z, a0.w, a1.x, a1.y, a1.z, a1.w};
        u16x8 hi, lo;
#pragma unroll
        for (int j = 0; j < 8; ++j) {
            unsigned short hh = f2bf_rn(qv[j]);
            hi[j] = hh; lo[j] = f2bf_rn(qv[j] - bf2f(hh));
        }
        *reinterpret_cast<u16x8*>(&SM[QH + r * 40 + c0]) = hi;
        *reinterpret_cast<u16x8*>(&SM[QL + r * 40 + c0]) = lo;

        float4 k0 = *reinterpret_cast<const float4*>(&kg[r * 32 + c0]);
        float4 k1 = *reinterpret_cast<const float4*>(&kg[r * 32 + c0 + 4]);
        float kv[8] = {k0.x, k0.y, k0.z, k0.w, k1.x, k1.y, k1.z, k1.w};
#pragma unroll
        for (int j = 0; j < 8; ++j) {
            unsigned short hh = f2bf_rn(kv[j]);
            hi[j] = hh; lo[j] = f2bf_rn(kv[j] - bf2f(hh));
        }
        *reinterpret_cast<u16x8*>(&SM[KH + r * 40 + c0]) = hi;
        *reinterpret_cast<u16x8*>(&SM[KL + r * 40 + c0]) = lo;

        float4 v0 = *reinterpret_cast<const float4*>(&vg[r * 32 + c0]);
        float4 v1 = *reinterpret_cast<const float4*>(&vg[r * 32 + c0 + 4]);
        float vv[8] = {v0.x, v0.y, v0.z, v0.w, v1.x, v1.y, v1.z, v1.w};
#pragma unroll
        for (int u = 0; u < 8; ++u) {
            const int d = c0 + u;
            unsigned short hh = f2bf_rn(vv[u]);
            SM[VTH + d * 72 + r] = hh;
            SM[VTL + d * 72 + r] = f2bf_rn(vv[u] - bf2f(hh));
        }
    }
    __syncthreads();

    float bias[4][4];
#pragma unroll
    for (int reg = 0; reg < 4; ++reg)
#pragma unroll
        for (int c = 0; c < 4; ++c)
            bias[reg][c] = bias_hn[(h << 12) + ((wv * 16 + lg * 4 + reg) << 6) + c * 16 + lr];

    const int ar = wv * 16 + lr;
    bf16x8 qa_h = *reinterpret_cast<const bf16x8*>(&SM[QH + ar * 40 + lg * 8]);
    bf16x8 qa_l = *reinterpret_cast<const bf16x8*>(&SM[QL + ar * 40 + lg * 8]);
    f32x4 S[4];
#pragma unroll
    for (int c = 0; c < 4; ++c) {
        const int br = c * 16 + lr;
        bf16x8 kb_h = *reinterpret_cast<const bf16x8*>(&SM[KH + br * 40 + lg * 8]);
        bf16x8 kb_l = *reinterpret_cast<const bf16x8*>(&SM[KL + br * 40 + lg * 8]);
        f32x4 s = (f32x4){0.f, 0.f, 0.f, 0.f};
        s = __builtin_amdgcn_mfma_f32_16x16x32_bf16(qa_h, kb_h, s, 0, 0, 0);
        s = __builtin_amdgcn_mfma_f32_16x16x32_bf16(qa_h, kb_l, s, 0, 0, 0);
        s = __builtin_amdgcn_mfma_f32_16x16x32_bf16(qa_l, kb_h, s, 0, 0, 0);
        S[c] = s;
    }
    __syncthreads();   // Q/K region dead -> reusable for P

    const float scale = 0.1767766952966369f;  // 32^-0.5
    float p[4][4], mx[4], sm[4];
#pragma unroll
    for (int reg = 0; reg < 4; ++reg) mx[reg] = -1e30f;
#pragma unroll
    for (int reg = 0; reg < 4; ++reg)
#pragma unroll
        for (int c = 0; c < 4; ++c) {
            float s = fmaf(S[c][reg], scale, bias[reg][c]);
            p[reg][c] = s;
            mx[reg] = fmaxf(mx[reg], s);
        }
#pragma unroll
    for (int reg = 0; reg < 4; ++reg) {
        mx[reg] = fmaxf(mx[reg], __shfl_xor(mx[reg], 1));
        mx[reg] = fmaxf(mx[reg], __shfl_xor(mx[reg], 2));
        mx[reg] = fmaxf(mx[reg], __shfl_xor(mx[reg], 4));
        mx[reg] = fmaxf(mx[reg], __shfl_xor(mx[reg], 8));
        sm[reg] = 0.f;
    }
#pragma unroll
    for (int reg = 0; reg < 4; ++reg)
#pragma unroll
        for (int c = 0; c < 4; ++c) {
            float e = __expf(p[reg][c] - mx[reg]);
            p[reg][c] = e;
            sm[reg] += e;
        }
#pragma unroll
    for (int reg = 0; reg < 4; ++reg) {
        sm[reg] += __shfl_xor(sm[reg], 1);
        sm[reg] += __shfl_xor(sm[reg], 2);
        sm[reg] += __shfl_xor(sm[reg], 4);
        sm[reg] += __shfl_xor(sm[reg], 8);
        const float inv = 1.0f / sm[reg];
#pragma unroll
        for (int c = 0; c < 4; ++c) p[reg][c] *= inv;
    }

    const size_t amb = (size_t)bh * 4096;
#pragma unroll
    for (int reg = 0; reg < 4; ++reg) {
        const int R = wv * 16 + lg * 4 + reg;
#pragma unroll
        for (int c = 0; c < 4; ++c) {
            const int C = c * 16 + lr;
            const float own = p[reg][c];
            attn_map[amb + R * 64 + C] = own;
            const float mate = __shfl_xor(own, 1);
            if (!(lr & 1)) {
                unsigned short h0 = f2bf_rn(own);
                unsigned short l0 = f2bf_rn(own - bf2f(h0));
                unsigned short h1 = f2bf_rn(mate);
                unsigned short l1 = f2bf_rn(mate - bf2f(h1));
                *reinterpret_cast<unsigned*>(&SM[PH + R * 72 + C]) =
                    (unsigned)h0 | ((unsigned)h1 << 16);
                *reinterpret_cast<unsigned*>(&SM[PL + R * 72 + C]) =
                    (unsigned)l0 | ((unsigned)l1 << 16);
            }
        }
    }
    // no barrier: wave w's PV a-frags read rows 16wv..16wv+15 = its own writes

    f32x4 O[2];
    O[0] = (f32x4){0.f, 0.f, 0.f, 0.f};
    O[1] = (f32x4){0.f, 0.f, 0.f, 0.f};
#pragma unroll
    for (int kk = 0; kk < 2; ++kk) {
        const int pr = wv * 16 + lr;
        bf16x8 pa_h = *reinterpret_cast<const bf16x8*>(&SM[PH + pr * 72 + kk * 32 + lg * 8]);
        bf16x8 pa_l = *reinterpret_cast<const bf16x8*>(&SM[PL + pr * 72 + kk * 32 + lg * 8]);
#pragma unroll
        for (int n = 0; n < 2; ++n) {
            const int vr = n * 16 + lr;
            bf16x8 vb_h = *reinterpret_cast<const bf16x8*>(&SM[VTH + vr * 72 + kk * 32 + lg * 8]);
            bf16x8 vb_l = *reinterpret_cast<const bf16x8*>(&SM[VTL + vr * 72 + kk * 32 + lg * 8]);
            O[n] = __builtin_amdgcn_mfma_f32_16x16x32_bf16(pa_h, vb_h, O[n], 0, 0, 0);
            O[n] = __builtin_amdgcn_mfma_f32_16x16x32_bf16(pa_h, vb_l, O[n], 0, 0, 0);
            O[n] = __builtin_amdgcn_mfma_f32_16x16x32_bf16(pa_l, vb_h, O[n], 0, 0, 0);
        }
    }

    const int mb = b >> 1;
#pragma unroll
    for (int n = 0; n < 2; ++n)
#pragma unroll
        for (int reg = 0; reg < 4; ++reg) {
            const int R  = wv * 16 + lg * 4 + reg;
            const int d  = n * 16 + lr;
            const int rl = (b & 1) * 64 + R;
            const float o = O[n][reg];
            unsigned short oh = f2bf_rn(o);
            unsigned short ol = f2bf_rn(o - bf2f(oh));
            size_t off = (size_t)mb * 65536 + (size_t)h * 4096
                       + (size_t)(d >> 3) * 1024 + (size_t)rl * 8 + (d & 7);
            avh[off] = oh;
            avl[off] = ol;
        }
}

// ---------------------------------------------------------------------------
extern "C" void kernel_launch(void* const* d_in, const int* in_sizes, int n_in,
                              void* d_out, int out_size, void* d_ws, size_t ws_size,
                              hipStream_t stream) {
    const float* x          = (const float*)d_in[0];
    const float* qkv_w      = (const float*)d_in[1];
    const float* proj_w     = (const float*)d_in[2];
    const float* proj_b     = (const float*)d_in[3];
    const float* bias_table = (const float*)d_in[4];
    const int*   rel_index  = (const int*)d_in[5];

    float* out      = (float*)d_out;                           // [131072][512]
    float* attn_map = (float*)d_out + (size_t)M_ROWS * C_DIM;  // [B][H][64][64]

    // d_ws: Xh | Xl (tiled bf16) | qkv fp32   (~1.074 GB, same as R1-R6)
    unsigned short* Xh  = (unsigned short*)d_ws;
    unsigned short* Xl  = Xh + (size_t)M_ROWS * 512;
    float*          qkv = (float*)(Xl + (size_t)M_ROWS * 512);
    unsigned short* avh = Xh;   // alias: dead after QKV GEMM
    unsigned short* avl = Xl;

    // parking: qkv_w split -> attn_map region (dead until attn overwrites);
    // proj_w split -> qkv head (dead after attn); bias_hn -> out head
    // (out written only by the final proj GEMM).
    unsigned short* qwTh = (unsigned short*)attn_map;
    unsigned short* qwTl = qwTh + (size_t)1536 * 512;
    unsigned short* pwTh = (unsigned short*)qkv;
    unsigned short* pwTl = pwTh + (size_t)512 * 512;
    float* bias_hn = out;   // 65536 floats at head of out region

    bias_expand_kernel<<<256, 256, 0, stream>>>(bias_table, rel_index, bias_hn);
    xsplit_kernel<<<M_ROWS * 512 / 2048, 256, 0, stream>>>(x, Xh, Xl);
    wsplit_kernel<<<384, 256, 0, stream>>>(qkv_w, qwTh, qwTl, 1536);
    gemm_mfma_kernel<<<dim3(12, 1024), 512, 0, stream>>>(
        Xh, Xl, qwTh, qwTl, 0, qkv, nullptr, nullptr, 1536, 12);
    attn_kernel<<<B_WIN * H_HEADS, 256, 0, stream>>>(
        qkv, bias_hn, attn_map, avh, avl);
    wsplit_kernel<<<128, 256, 0, stream>>>(proj_w, pwTh, pwTl, 512);
    gemm_mfma_kernel<<<dim3(4, 1024), 512, 0, stream>>>(
        avh, avl, pwTh, pwTl, 1, nullptr, proj_b, out, 512, 4);
}